// Round 1
// baseline (125.376 us; speedup 1.0000x reference)
//
#include <hip/hip_runtime.h>
#include <stdint.h>

#define N_ROWS 8192
#define FEAT   256
#define YSPLIT 16
#define CPB    (N_ROWS / YSPLIT)   // 512 cols per kmain block
#define CT     64                  // cols staged per chunk (32 KB)

typedef __bf16 bf16x8 __attribute__((ext_vector_type(8)));
typedef float  f32x4  __attribute__((ext_vector_type(4)));

__device__ __forceinline__ unsigned short f2bf(float x) {
    union { float f; uint32_t u; } v; v.f = x;
    uint32_t u = v.u;
    return (unsigned short)((u + 0x7FFFu + ((u >> 16) & 1u)) >> 16);
}

__device__ __forceinline__ void gld16(const unsigned short* g, unsigned short* l) {
    // direct global->LDS, 16 B per lane; LDS dest must be wave-linear (it is)
    __builtin_amdgcn_global_load_lds((__attribute__((address_space(1))) void*)g,
                                     (__attribute__((address_space(3))) void*)l,
                                     16, 0, 0);
}

// ---- Kernel 1: normalize rows -> bf16 copy (16B-chunk XOR-swizzled rows);
//      fused positive-pair dot. 4 waves/block = 4 consecutive rows.
__global__ void knorm(const float* __restrict__ feat,
                      unsigned short* __restrict__ fb,
                      float* __restrict__ pos) {
    __shared__ float ex[4][FEAT];
    int wave = threadIdx.x >> 6;
    int lane = threadIdx.x & 63;
    int row  = blockIdx.x * 4 + wave;
    float4 v = ((const float4*)(feat + row * FEAT))[lane];
    float ss = v.x*v.x + v.y*v.y + v.z*v.z + v.w*v.w;
    #pragma unroll
    for (int off = 1; off < 64; off <<= 1) ss += __shfl_xor(ss, off);
    float inv = 1.0f / fmaxf(sqrtf(ss), 1e-12f);
    float4 o; o.x = v.x*inv; o.y = v.y*inv; o.z = v.z*inv; o.w = v.w*inv;
    ushort4 b;
    b.x = f2bf(o.x); b.y = f2bf(o.y); b.z = f2bf(o.z); b.w = f2bf(o.w);
    // row layout: 32 chunks of 16B; chunk c stored at position c ^ (row&7).
    // each lane holds 8B (half a chunk): 16B-chunk = lane>>1, half = lane&1.
    int sidx = (((lane >> 1) ^ (row & 7)) << 1) | (lane & 1);
    ((ushort4*)(fb + row * FEAT))[sidx] = b;
    // exchange normalized rows for the fp32 positive dot
    ((float4*)ex[wave])[lane] = o;
    __syncthreads();
    float4 p = ((float4*)ex[wave ^ 1])[lane];
    float d = o.x*p.x + o.y*p.y + o.z*p.z + o.w*p.w;
    #pragma unroll
    for (int off = 1; off < 64; off <<= 1) d += __shfl_xor(d, off);
    if (lane == 0) pos[row] = d;
}

// ---- Kernel 2: tiled f@f^T with fused fixed-max exp-sum ------------------
// grid (32, YSPLIT): x = 256-row block (4 waves x 64 rows), y = CPB cols.
// Each wave holds 64 rows of A in registers (af[4][8], 128 VGPR) so one
// ds_read_b128 B-fragment feeds 4 MFMAs. B staged to LDS double-buffered
// via global_load_lds (linear dest; swizzle pre-applied in fb's layout).
__global__ __launch_bounds__(256, 2)
void kmain(const unsigned short* __restrict__ fb, float* __restrict__ partial) {
    __shared__ unsigned short bufA[CT * FEAT];   // 32 KB
    __shared__ unsigned short bufB[CT * FEAT];   // 32 KB
    const int t    = threadIdx.x;
    const int lane = t & 63;
    const int wave = t >> 6;          // 0..3
    const int quad = lane >> 4;       // 0..3
    const int l15  = lane & 15;
    const int rw    = blockIdx.x * 256 + wave * 64;
    const int cbase = blockIdx.y * CPB;
    const float Kc = 20.60992915555662f;          // log2(e)/0.07

#define STAGE(DST, CC0) do {                                                  \
    const unsigned short* sp_ = fb + (size_t)(cbase + (CC0)) * FEAT + t * 8;  \
    unsigned short* dp_ = (DST) + t * 8;                                      \
    _Pragma("unroll")                                                         \
    for (int i_ = 0; i_ < 8; ++i_)                                            \
        gld16(sp_ + i_ * 2048, dp_ + i_ * 2048);                              \
} while (0)

    STAGE(bufA, 0);    // chunk 0 in flight while we load A fragments

    // A fragments: 64 rows x K=256 resident in registers (128 VGPRs)
    bf16x8 af[4][8];
    #pragma unroll
    for (int rf = 0; rf < 4; ++rf)
        #pragma unroll
        for (int ks = 0; ks < 8; ++ks) {
            int row = rw + rf * 16 + l15;
            int ch  = (ks * 4 + quad) ^ (row & 7);   // undo layout swizzle
            af[rf][ks] = *(const bf16x8*)(fb + row * FEAT + ch * 8);
        }

    float lsum[4][4] = {{0.f,0.f,0.f,0.f},{0.f,0.f,0.f,0.f},
                        {0.f,0.f,0.f,0.f},{0.f,0.f,0.f,0.f}};

#define EPI(AC, RF) do {                                                      \
    const int rb_ = rw + (RF) * 16;                                           \
    const bool dg_ = (cg == rb_);          /* 16-aligned tiles: overlap==eq */\
    _Pragma("unroll")                                                         \
    for (int r_ = 0; r_ < 4; ++r_) {                                          \
        float e_ = __builtin_amdgcn_exp2f(fmaf((AC)[r_], Kc, -Kc));           \
        if (dg_ && (rb_ + quad * 4 + r_ == C)) e_ = 0.f;  /* mask j == i */   \
        lsum[(RF)][r_] += e_;                                                 \
    }                                                                         \
} while (0)

#define COMPUTE(BS, CC0) do {                                                 \
    _Pragma("unroll")                                                         \
    for (int g = 0; g < 4; ++g) {                                             \
        const int cg = cbase + (CC0) + g * 16;                                \
        const int C  = cg + l15;                                              \
        f32x4 ac0 = {0.f,0.f,0.f,0.f};                                        \
        f32x4 ac1 = {0.f,0.f,0.f,0.f};                                        \
        f32x4 ac2 = {0.f,0.f,0.f,0.f};                                        \
        f32x4 ac3 = {0.f,0.f,0.f,0.f};                                        \
        _Pragma("unroll")                                                     \
        for (int ks = 0; ks < 8; ++ks) {                                      \
            bf16x8 b = *(const bf16x8*)((BS) + (g * 16 + l15) * FEAT          \
                                        + (((ks * 4 + quad) ^ (l15 & 7)) * 8)); \
            ac0 = __builtin_amdgcn_mfma_f32_16x16x32_bf16(af[0][ks], b, ac0, 0, 0, 0); \
            ac1 = __builtin_amdgcn_mfma_f32_16x16x32_bf16(af[1][ks], b, ac1, 0, 0, 0); \
            ac2 = __builtin_amdgcn_mfma_f32_16x16x32_bf16(af[2][ks], b, ac2, 0, 0, 0); \
            ac3 = __builtin_amdgcn_mfma_f32_16x16x32_bf16(af[3][ks], b, ac3, 0, 0, 0); \
        }                                                                     \
        EPI(ac0, 0); EPI(ac1, 1); EPI(ac2, 2); EPI(ac3, 3);                   \
    }                                                                         \
} while (0)

    asm volatile("s_waitcnt vmcnt(0)" ::: "memory");
    __builtin_amdgcn_s_barrier();
    for (int ct2 = 0; ct2 < CPB / CT; ct2 += 2) {
        // phase A: prefetch next chunk into bufB, compute from bufA
        STAGE(bufB, (ct2 + 1) * CT);
        COMPUTE(bufA, ct2 * CT);
        asm volatile("s_waitcnt vmcnt(0)" ::: "memory");
        __builtin_amdgcn_s_barrier();
        // phase B: prefetch next chunk into bufA, compute from bufB
        if (ct2 + 2 < CPB / CT) STAGE(bufA, (ct2 + 2) * CT);
        COMPUTE(bufB, (ct2 + 1) * CT);
        asm volatile("s_waitcnt vmcnt(0)" ::: "memory");
        __builtin_amdgcn_s_barrier();
    }

    #pragma unroll
    for (int rf = 0; rf < 4; ++rf)
        #pragma unroll
        for (int r = 0; r < 4; ++r) {
            float v = lsum[rf][r];
            v += __shfl_xor(v, 1);
            v += __shfl_xor(v, 2);
            v += __shfl_xor(v, 4);
            v += __shfl_xor(v, 8);
            lsum[rf][r] = v;
        }
    if (l15 == 0) {
        #pragma unroll
        for (int rf = 0; rf < 4; ++rf)
            #pragma unroll
            for (int r = 0; r < 4; ++r) {
                int row = rw + rf * 16 + quad * 4 + r;
                partial[blockIdx.y * N_ROWS + row] = lsum[rf][r];
            }
    }
#undef STAGE
#undef COMPUTE
#undef EPI
}

// ---- Kernel 3: per-row loss + block tree-reduce (no same-address atomics)
__global__ void kreduce(const float* __restrict__ partial,
                        const float* __restrict__ pos,
                        float* __restrict__ bsum) {
    __shared__ float red[4];
    int row  = blockIdx.x * 256 + threadIdx.x;
    int wave = threadIdx.x >> 6;
    int lane = threadIdx.x & 63;
    float L = 0.f;
    #pragma unroll
    for (int p = 0; p < YSPLIT; ++p) L += partial[p * N_ROWS + row];
    const float invT = 14.285714285714286f;
    // loss_i = (1 - pos_i)/T + ln2 * log2(L)   (v_log_f32 is log2)
    float loss = invT * (1.0f - pos[row])
               + 0.6931471805599453f * __builtin_amdgcn_logf(L);
    #pragma unroll
    for (int off = 1; off < 64; off <<= 1) loss += __shfl_xor(loss, off);
    if (lane == 0) red[wave] = loss;
    __syncthreads();
    if (threadIdx.x == 0)
        bsum[blockIdx.x] = red[0] + red[1] + red[2] + red[3];
}

// ---- Kernel 4: final 32 -> 1 ---------------------------------------------
__global__ void kfinal(const float* __restrict__ bsum, float* __restrict__ out) {
    int lane = threadIdx.x;
    float v = (lane < 32) ? bsum[lane] : 0.f;
    #pragma unroll
    for (int off = 1; off < 32; off <<= 1) v += __shfl_xor(v, off);
    if (lane == 0) out[0] = v * (1.0f / 8192.0f);
}

extern "C" void kernel_launch(void* const* d_in, const int* in_sizes, int n_in,
                              void* d_out, int out_size, void* d_ws, size_t ws_size,
                              hipStream_t stream) {
    const float* feat = (const float*)d_in[0];
    float* out = (float*)d_out;
    char* ws = (char*)d_ws;
    unsigned short* fb      = (unsigned short*)ws;                    // 4 MB bf16 (swizzled rows)
    float*          partial = (float*)(ws + (4u << 20));              // 512 KB
    float*          pos     = (float*)(ws + (4u << 20) + (1u << 19)); // 32 KB
    float*          bsum    = (float*)(ws + (4u << 20) + (1u << 19) + (1u << 15));

    knorm<<<N_ROWS / 4, 256, 0, stream>>>(feat, fb, pos);
    kmain<<<dim3(32, YSPLIT), 256, 0, stream>>>(fb, partial);
    kreduce<<<N_ROWS / 256, 256, 0, stream>>>(partial, pos, bsum);
    kfinal<<<1, 64, 0, stream>>>(bsum, out);
}

// Round 2
// 102.174 us; speedup vs baseline: 1.2271x; 1.2271x over previous
//
#include <hip/hip_runtime.h>
#include <stdint.h>

#define N_ROWS 8192
#define FEAT   256
#define YSPLIT 16
#define CPB    (N_ROWS / YSPLIT)   // 512 cols per kmain block
#define CT     64                  // cols staged per chunk (32 KB)

typedef __bf16 bf16x8 __attribute__((ext_vector_type(8)));
typedef float  f32x4  __attribute__((ext_vector_type(4)));

__device__ __forceinline__ unsigned short f2bf(float x) {
    union { float f; uint32_t u; } v; v.f = x;
    uint32_t u = v.u;
    return (unsigned short)((u + 0x7FFFu + ((u >> 16) & 1u)) >> 16);
}

__device__ __forceinline__ void gld16(const unsigned short* g, unsigned short* l) {
    // direct global->LDS, 16 B per lane; LDS dest must be wave-linear (it is)
    __builtin_amdgcn_global_load_lds((__attribute__((address_space(1))) void*)g,
                                     (__attribute__((address_space(3))) void*)l,
                                     16, 0, 0);
}

// ---- Kernel 1: normalize rows -> bf16 copy (16B-chunk XOR-swizzled rows);
//      fused positive-pair dot. 4 waves/block = 4 consecutive rows.
__global__ void knorm(const float* __restrict__ feat,
                      unsigned short* __restrict__ fb,
                      float* __restrict__ pos) {
    __shared__ float ex[4][FEAT];
    int wave = threadIdx.x >> 6;
    int lane = threadIdx.x & 63;
    int row  = blockIdx.x * 4 + wave;
    float4 v = ((const float4*)(feat + row * FEAT))[lane];
    float ss = v.x*v.x + v.y*v.y + v.z*v.z + v.w*v.w;
    #pragma unroll
    for (int off = 1; off < 64; off <<= 1) ss += __shfl_xor(ss, off);
    float inv = 1.0f / fmaxf(sqrtf(ss), 1e-12f);
    float4 o; o.x = v.x*inv; o.y = v.y*inv; o.z = v.z*inv; o.w = v.w*inv;
    ushort4 b;
    b.x = f2bf(o.x); b.y = f2bf(o.y); b.z = f2bf(o.z); b.w = f2bf(o.w);
    // row layout: 32 chunks of 16B; chunk c stored at position c ^ (row&7).
    // each lane holds 8B (half a chunk): 16B-chunk = lane>>1, half = lane&1.
    int sidx = (((lane >> 1) ^ (row & 7)) << 1) | (lane & 1);
    ((ushort4*)(fb + row * FEAT))[sidx] = b;
    // exchange normalized rows for the fp32 positive dot
    ((float4*)ex[wave])[lane] = o;
    __syncthreads();
    float4 p = ((float4*)ex[wave ^ 1])[lane];
    float d = o.x*p.x + o.y*p.y + o.z*p.z + o.w*p.w;
    #pragma unroll
    for (int off = 1; off < 64; off <<= 1) d += __shfl_xor(d, off);
    if (lane == 0) pos[row] = d;
}

// ---- Kernel 2: tiled f@f^T with fused fixed-max exp-sum ------------------
// grid (32, YSPLIT): x = 256-row block (4 waves x 64 rows), y = CPB cols.
// Each wave holds 64 rows of A in registers (af[4][8], 128 VGPR) so one
// ds_read_b128 B-fragment feeds 4 MFMAs. B staged to LDS double-buffered
// via global_load_lds (linear dest; swizzle pre-applied in fb's layout).
// launch_bounds(256,1): round-1's (256,2) capped arch VGPRs at 128 -> the
// 128-reg af[] array consumed the whole file and everything else spilled
// (WRITE_SIZE 41 MB of scratch). Budget 512 removes the cap; ~200 live
// regs still allows 2 waves/SIMD at runtime.
__global__ __launch_bounds__(256, 1)
void kmain(const unsigned short* __restrict__ fb, float* __restrict__ partial) {
    __shared__ unsigned short bufA[CT * FEAT];   // 32 KB
    __shared__ unsigned short bufB[CT * FEAT];   // 32 KB
    const int t    = threadIdx.x;
    const int lane = t & 63;
    const int wave = t >> 6;          // 0..3
    const int quad = lane >> 4;       // 0..3
    const int l15  = lane & 15;
    const int rw    = blockIdx.x * 256 + wave * 64;
    const int cbase = blockIdx.y * CPB;
    const float Kc = 20.60992915555662f;          // log2(e)/0.07

#define STAGE(DST, CC0) do {                                                  \
    const unsigned short* sp_ = fb + (size_t)(cbase + (CC0)) * FEAT + t * 8;  \
    unsigned short* dp_ = (DST) + t * 8;                                      \
    _Pragma("unroll")                                                         \
    for (int i_ = 0; i_ < 8; ++i_)                                            \
        gld16(sp_ + i_ * 2048, dp_ + i_ * 2048);                              \
} while (0)

    STAGE(bufA, 0);    // chunk 0 in flight while we load A fragments

    // A fragments: 64 rows x K=256 resident in registers (128 VGPRs)
    bf16x8 af[4][8];
    #pragma unroll
    for (int rf = 0; rf < 4; ++rf)
        #pragma unroll
        for (int ks = 0; ks < 8; ++ks) {
            int row = rw + rf * 16 + l15;
            int ch  = (ks * 4 + quad) ^ (row & 7);   // undo layout swizzle
            af[rf][ks] = *(const bf16x8*)(fb + row * FEAT + ch * 8);
        }

    float lsum[4][4] = {{0.f,0.f,0.f,0.f},{0.f,0.f,0.f,0.f},
                        {0.f,0.f,0.f,0.f},{0.f,0.f,0.f,0.f}};

#define EPI(AC, RF) do {                                                      \
    const int rb_ = rw + (RF) * 16;                                           \
    const bool dg_ = (cg == rb_);          /* 16-aligned tiles: overlap==eq */\
    _Pragma("unroll")                                                         \
    for (int r_ = 0; r_ < 4; ++r_) {                                          \
        float e_ = __builtin_amdgcn_exp2f(fmaf((AC)[r_], Kc, -Kc));           \
        if (dg_ && (rb_ + quad * 4 + r_ == C)) e_ = 0.f;  /* mask j == i */   \
        lsum[(RF)][r_] += e_;                                                 \
    }                                                                         \
} while (0)

#define COMPUTE(BS, CC0) do {                                                 \
    _Pragma("unroll")                                                         \
    for (int g = 0; g < 4; ++g) {                                             \
        const int cg = cbase + (CC0) + g * 16;                                \
        const int C  = cg + l15;                                              \
        f32x4 ac0 = {0.f,0.f,0.f,0.f};                                        \
        f32x4 ac1 = {0.f,0.f,0.f,0.f};                                        \
        f32x4 ac2 = {0.f,0.f,0.f,0.f};                                        \
        f32x4 ac3 = {0.f,0.f,0.f,0.f};                                        \
        _Pragma("unroll")                                                     \
        for (int ks = 0; ks < 8; ++ks) {                                      \
            bf16x8 b = *(const bf16x8*)((BS) + (g * 16 + l15) * FEAT          \
                                        + (((ks * 4 + quad) ^ (l15 & 7)) * 8)); \
            ac0 = __builtin_amdgcn_mfma_f32_16x16x32_bf16(af[0][ks], b, ac0, 0, 0, 0); \
            ac1 = __builtin_amdgcn_mfma_f32_16x16x32_bf16(af[1][ks], b, ac1, 0, 0, 0); \
            ac2 = __builtin_amdgcn_mfma_f32_16x16x32_bf16(af[2][ks], b, ac2, 0, 0, 0); \
            ac3 = __builtin_amdgcn_mfma_f32_16x16x32_bf16(af[3][ks], b, ac3, 0, 0, 0); \
        }                                                                     \
        EPI(ac0, 0); EPI(ac1, 1); EPI(ac2, 2); EPI(ac3, 3);                   \
    }                                                                         \
} while (0)

    asm volatile("s_waitcnt vmcnt(0)" ::: "memory");
    __builtin_amdgcn_s_barrier();
    for (int ct2 = 0; ct2 < CPB / CT; ct2 += 2) {
        // phase A: prefetch next chunk into bufB, compute from bufA
        STAGE(bufB, (ct2 + 1) * CT);
        COMPUTE(bufA, ct2 * CT);
        asm volatile("s_waitcnt vmcnt(0)" ::: "memory");
        __builtin_amdgcn_s_barrier();
        // phase B: prefetch next chunk into bufA, compute from bufB
        if (ct2 + 2 < CPB / CT) STAGE(bufA, (ct2 + 2) * CT);
        COMPUTE(bufB, (ct2 + 1) * CT);
        asm volatile("s_waitcnt vmcnt(0)" ::: "memory");
        __builtin_amdgcn_s_barrier();
    }

    #pragma unroll
    for (int rf = 0; rf < 4; ++rf)
        #pragma unroll
        for (int r = 0; r < 4; ++r) {
            float v = lsum[rf][r];
            v += __shfl_xor(v, 1);
            v += __shfl_xor(v, 2);
            v += __shfl_xor(v, 4);
            v += __shfl_xor(v, 8);
            lsum[rf][r] = v;
        }
    if (l15 == 0) {
        #pragma unroll
        for (int rf = 0; rf < 4; ++rf)
            #pragma unroll
            for (int r = 0; r < 4; ++r) {
                int row = rw + rf * 16 + quad * 4 + r;
                partial[blockIdx.y * N_ROWS + row] = lsum[rf][r];
            }
    }
#undef STAGE
#undef COMPUTE
#undef EPI
}

// ---- Kernel 3: per-row loss + block tree-reduce (no same-address atomics)
__global__ void kreduce(const float* __restrict__ partial,
                        const float* __restrict__ pos,
                        float* __restrict__ bsum) {
    __shared__ float red[4];
    int row  = blockIdx.x * 256 + threadIdx.x;
    int wave = threadIdx.x >> 6;
    int lane = threadIdx.x & 63;
    float L = 0.f;
    #pragma unroll
    for (int p = 0; p < YSPLIT; ++p) L += partial[p * N_ROWS + row];
    const float invT = 14.285714285714286f;
    // loss_i = (1 - pos_i)/T + ln2 * log2(L)   (v_log_f32 is log2)
    float loss = invT * (1.0f - pos[row])
               + 0.6931471805599453f * __builtin_amdgcn_logf(L);
    #pragma unroll
    for (int off = 1; off < 64; off <<= 1) loss += __shfl_xor(loss, off);
    if (lane == 0) red[wave] = loss;
    __syncthreads();
    if (threadIdx.x == 0)
        bsum[blockIdx.x] = red[0] + red[1] + red[2] + red[3];
}

// ---- Kernel 4: final 32 -> 1 ---------------------------------------------
__global__ void kfinal(const float* __restrict__ bsum, float* __restrict__ out) {
    int lane = threadIdx.x;
    float v = (lane < 32) ? bsum[lane] : 0.f;
    #pragma unroll
    for (int off = 1; off < 32; off <<= 1) v += __shfl_xor(v, off);
    if (lane == 0) out[0] = v * (1.0f / 8192.0f);
}

extern "C" void kernel_launch(void* const* d_in, const int* in_sizes, int n_in,
                              void* d_out, int out_size, void* d_ws, size_t ws_size,
                              hipStream_t stream) {
    const float* feat = (const float*)d_in[0];
    float* out = (float*)d_out;
    char* ws = (char*)d_ws;
    unsigned short* fb      = (unsigned short*)ws;                    // 4 MB bf16 (swizzled rows)
    float*          partial = (float*)(ws + (4u << 20));              // 512 KB
    float*          pos     = (float*)(ws + (4u << 20) + (1u << 19)); // 32 KB
    float*          bsum    = (float*)(ws + (4u << 20) + (1u << 19) + (1u << 15));

    knorm<<<N_ROWS / 4, 256, 0, stream>>>(feat, fb, pos);
    kmain<<<dim3(32, YSPLIT), 256, 0, stream>>>(fb, partial);
    kreduce<<<N_ROWS / 256, 256, 0, stream>>>(partial, pos, bsum);
    kfinal<<<1, 64, 0, stream>>>(bsum, out);
}